// Round 1
// baseline (19342.998 us; speedup 1.0000x reference)
//
#include <hip/hip_runtime.h>
#include <hip/hip_bf16.h>
#include <math.h>

#define CDIV(a,b) (((a)+(b)-1)/(b))

// ---------------- problem constants ----------------
#define Bn   8
#define Nn   2000
#define En   512
#define HEN  1024
#define Dn   128
#define HDn  512
#define Pn   8
#define HDE  1024
#define IBn  64
#define TOPK 50

// ---------------- generic fp32 GEMM ----------------
// C[b] = act( op(A[b]) @ op(B[b]) + bias )   (optionally +=)
// A: TA ? (K,M) : (M,K)   B: TB ? (N,K) : (K,N)   C: (M,N) row-major
// ACT: 0 none, 1 relu, 2 gelu(exact)
#define BM 128
#define BN 128
#define BK 16

__device__ __forceinline__ float gelu_exact(float x) {
    return 0.5f * x * (1.0f + erff(x * 0.70710678118654752440f));
}

template<int ACT, bool TA, bool TB, bool ACCUM, bool UPPER>
__global__ __launch_bounds__(256) void gemm_k(
    const float* __restrict__ A, const float* __restrict__ B,
    const float* __restrict__ bias, float* __restrict__ C,
    int M, int N, int K,
    long long sA, long long sB, long long sC)
{
    if (UPPER && (int)blockIdx.x > (int)blockIdx.y) return;  // strictly-lower tile: skip (symmetric C)
    const int bz = blockIdx.z;
    A += (long long)bz * sA;
    B += (long long)bz * sB;
    C += (long long)bz * sC;
    const int bm0 = blockIdx.x * BM;
    const int bn0 = blockIdx.y * BN;

    __shared__ __align__(16) float As[BK][BM + 4];
    __shared__ __align__(16) float Bs[BK][BN + 4];

    const int tid = threadIdx.x;
    const int tx = tid & 15;        // 0..15 -> N micro
    const int ty = tid >> 4;        // 0..15 -> M micro

    float acc[8][8];
#pragma unroll
    for (int i = 0; i < 8; ++i)
#pragma unroll
        for (int j = 0; j < 8; ++j) acc[i][j] = 0.0f;

    for (int k0 = 0; k0 < K; k0 += BK) {
        // ---- load A tile into As[k][m] ----
        if (TA) {
            // A is (K, M), lda = M; coalesced along m
            const int m = tid & 127;
            const int kb = tid >> 7;
#pragma unroll
            for (int pass = 0; pass < 8; ++pass) {
                const int kk = kb + pass * 2;
                const int gm = bm0 + m, gk = k0 + kk;
                As[kk][m] = (gm < M && gk < K) ? A[(long long)gk * M + gm] : 0.0f;
            }
        } else {
            // A is (M, K), lda = K; coalesced along k (16-wide)
            const int kk = tid & 15;
            const int mb = tid >> 4;
#pragma unroll
            for (int pass = 0; pass < 8; ++pass) {
                const int m = mb + pass * 16;
                const int gm = bm0 + m, gk = k0 + kk;
                As[kk][m] = (gm < M && gk < K) ? A[(long long)gm * K + gk] : 0.0f;
            }
        }
        // ---- load B tile into Bs[k][n] ----
        if (TB) {
            // B is (N, K), ldb = K; coalesced along k
            const int kk = tid & 15;
            const int nb = tid >> 4;
#pragma unroll
            for (int pass = 0; pass < 8; ++pass) {
                const int n = nb + pass * 16;
                const int gn = bn0 + n, gk = k0 + kk;
                Bs[kk][n] = (gn < N && gk < K) ? B[(long long)gn * K + gk] : 0.0f;
            }
        } else {
            // B is (K, N), ldb = N; coalesced along n
            const int n = tid & 127;
            const int kb = tid >> 7;
#pragma unroll
            for (int pass = 0; pass < 8; ++pass) {
                const int kk = kb + pass * 2;
                const int gn = bn0 + n, gk = k0 + kk;
                Bs[kk][n] = (gn < N && gk < K) ? B[(long long)gk * N + gn] : 0.0f;
            }
        }
        __syncthreads();

#pragma unroll
        for (int k = 0; k < BK; ++k) {
            const float4 a0 = *(const float4*)(&As[k][ty * 4]);
            const float4 a1 = *(const float4*)(&As[k][64 + ty * 4]);
            const float4 b0 = *(const float4*)(&Bs[k][tx * 4]);
            const float4 b1 = *(const float4*)(&Bs[k][64 + tx * 4]);
            const float av[8] = {a0.x, a0.y, a0.z, a0.w, a1.x, a1.y, a1.z, a1.w};
            const float bv[8] = {b0.x, b0.y, b0.z, b0.w, b1.x, b1.y, b1.z, b1.w};
#pragma unroll
            for (int i = 0; i < 8; ++i)
#pragma unroll
                for (int j = 0; j < 8; ++j)
                    acc[i][j] = fmaf(av[i], bv[j], acc[i][j]);
        }
        __syncthreads();
    }

    // ---- epilogue ----
#pragma unroll
    for (int i = 0; i < 8; ++i) {
        const int ml = (i < 4) ? (ty * 4 + i) : (64 + ty * 4 + (i - 4));
        const int gm = bm0 + ml;
        if (gm >= M) continue;
#pragma unroll
        for (int j = 0; j < 8; ++j) {
            const int nl = (j < 4) ? (tx * 4 + j) : (64 + tx * 4 + (j - 4));
            const int gn = bn0 + nl;
            if (gn >= N) continue;
            float v = acc[i][j];
            if (bias) v += bias[gn];
            if (ACT == 1) v = fmaxf(v, 0.0f);
            if (ACT == 2) v = gelu_exact(v);
            if (ACCUM) C[(long long)gm * N + gn] += v;
            else       C[(long long)gm * N + gn] = v;
        }
    }
}

// ---------------- gate * emb ----------------
__global__ void gate_k(const float* __restrict__ x, const float* __restrict__ gw,
                       const float* __restrict__ gb, const float* __restrict__ emb,
                       float* __restrict__ X)
{
    const long long total = (long long)Bn * Nn * En;
    const long long idx = (long long)blockIdx.x * 256 + threadIdx.x;
    if (idx >= total) return;
    const int e = (int)(idx % En);
    const long long bn = idx / En;
    const int n = (int)(bn % Nn);
    const float t = x[bn] * gw[e] + gb[e];
    const float s = 1.0f / (1.0f + expf(-t));
    X[idx] = s * emb[(long long)n * En + e];
}

// ---------------- mirror: lower blocks <- transpose(upper) ----------------
__global__ __launch_bounds__(256) void mirror_k(float* __restrict__ att)
{
    const int bi = blockIdx.x, bj = blockIdx.y;
    if (bi <= bj) return;                       // only strictly-lower 64x64 tiles
    float* A = att + (long long)blockIdx.z * Nn * Nn;
    __shared__ float t64[64][65];
    const int ti = threadIdx.x & 63;
    const int tj = threadIdx.x >> 6;            // 0..3
    const int i0 = bi * 64, j0 = bj * 64;
    for (int r = tj; r < 64; r += 4) {
        const int sr = j0 + r, sc = i0 + ti;    // source (upper) element
        t64[r][ti] = (sr < Nn && sc < Nn) ? A[(long long)sr * Nn + sc] : 0.0f;
    }
    __syncthreads();
    for (int r = tj; r < 64; r += 4) {
        const int dr = i0 + r, dc = j0 + ti;    // dest (lower) element
        if (dr < Nn && dc < Nn) A[(long long)dr * Nn + dc] = t64[ti][r];
    }
}

// ---------------- top-k threshold + masked softmax (per row) ----------------
__global__ __launch_bounds__(256) void topk_softmax_k(float* __restrict__ att)
{
    const long long row = blockIdx.x;
    float* r = att + row * Nn;
    __shared__ float vals[Nn];
    __shared__ unsigned hist[256];
    __shared__ float red[256];
    __shared__ unsigned sel_prefix;
    __shared__ int sel_k;
    const int t = threadIdx.x;

    for (int j = t; j < Nn; j += 256) vals[j] = r[j] * 0.125f;   // att / P
    __syncthreads();

    // radix select (values are >= 0 -> uint order == float order)
    unsigned prefix = 0;
    int kneed = TOPK;
    for (int shift = 24; shift >= 0; shift -= 8) {
        hist[t] = 0;
        __syncthreads();
        const unsigned pmask = (shift == 24) ? 0u : (0xFFFFFFFFu << (shift + 8));
        for (int j = t; j < Nn; j += 256) {
            const unsigned u = __float_as_uint(vals[j]);
            if ((u & pmask) == prefix) atomicAdd(&hist[(u >> shift) & 255u], 1u);
        }
        __syncthreads();
        if (t == 0) {
            int acc = 0, b = 255;
            for (; b >= 0; --b) {
                const int c = (int)hist[b];
                if (acc + c >= kneed) break;
                acc += c;
            }
            if (b < 0) b = 0;
            sel_prefix = prefix | ((unsigned)b << shift);
            sel_k = kneed - acc;
        }
        __syncthreads();
        prefix = sel_prefix;
        kneed = sel_k;
        __syncthreads();
    }
    const float thr = __uint_as_float(prefix);

    // row max (max over all == max over selected)
    float lm = -1e30f;
    for (int j = t; j < Nn; j += 256) lm = fmaxf(lm, vals[j]);
    red[t] = lm; __syncthreads();
    for (int s = 128; s > 0; s >>= 1) { if (t < s) red[t] = fmaxf(red[t], red[t + s]); __syncthreads(); }
    const float rowmax = red[0]; __syncthreads();

    // sum of exp over selected
    float ls = 0.0f;
    for (int j = t; j < Nn; j += 256)
        if (vals[j] >= thr) ls += expf(vals[j] - rowmax);
    red[t] = ls; __syncthreads();
    for (int s = 128; s > 0; s >>= 1) { if (t < s) red[t] += red[t + s]; __syncthreads(); }
    const float Z = red[0]; __syncthreads();

    for (int j = t; j < Nn; j += 256) {
        const float v = vals[j];
        r[j] = (v >= thr) ? (expf(v - rowmax) / Z) : 0.0f;   // exp(NEG-max) underflows to 0 in fp32
    }
}

// ---------------- column sums of (adj + I) -> rsqrt ----------------
__global__ void colsum_k(const float* __restrict__ att, float* __restrict__ dinv)
{
    const int b = blockIdx.y;
    const int i = blockIdx.x * 256 + threadIdx.x;
    if (i >= Nn) return;
    const float* A = att + (long long)b * Nn * Nn;
    float s = 1.0f;                               // + identity diagonal
    for (int j = 0; j < Nn; ++j) s += A[(long long)j * Nn + i];
    dinv[b * Nn + i] = rsqrtf(s);
}

// ---------------- An[j][i] = (adj[j][i] + (i==j)) * dinv[j]*dinv[i] ----------------
__global__ void norm_adj_k(float* __restrict__ att, const float* __restrict__ dinv)
{
    const int i = blockIdx.x * 256 + threadIdx.x;
    if (i >= Nn) return;
    const int j = blockIdx.y;
    const int b = blockIdx.z;
    const long long off = ((long long)b * Nn + j) * Nn + i;
    float v = att[off] + ((i == j) ? 1.0f : 0.0f);
    att[off] = v * dinv[b * Nn + j] * dinv[b * Nn + i];
}

// ---------------- mean over nodes ----------------
__global__ void mean_k(const float* __restrict__ nout, float* __restrict__ g)
{
    const int b = blockIdx.x;
    const int d = threadIdx.x;                    // Dn = 128 threads
    float s = 0.0f;
    for (int i = 0; i < Nn; ++i) s += nout[((long long)b * Nn + i) * Dn + d];
    g[b * Dn + d] = s / (float)Nn;
}

// ---------------- VIB head ----------------
__global__ void vib_k(const float* __restrict__ g, const float* __restrict__ eps,
                      float* __restrict__ mu_out, float* __restrict__ std_out,
                      float* __restrict__ z)
{
    const int t = blockIdx.x * 256 + threadIdx.x;
    if (t >= Bn * IBn) return;
    const int b = t / IBn, d = t % IBn;
    const float mu = g[b * Dn + d];
    const float x = g[b * Dn + IBn + d] - (float)IBn;
    const float sp = (x > 0.0f) ? (x + log1pf(expf(-x))) : log1pf(expf(x));
    mu_out[t] = mu;
    std_out[t] = sp;
    z[t] = mu + eps[t] * sp;
}

// ---------------- decoder layer 1 (fused scale/shift + relu) ----------------
__global__ void dec1_k(const float* __restrict__ z, const float* __restrict__ w1,
                       const float* __restrict__ b1, const float* __restrict__ gamma,
                       const float* __restrict__ beta, float* __restrict__ h)
{
    const int idx = blockIdx.x * 256 + threadIdx.x;
    if (idx >= Bn * HDE) return;
    const int b = idx / HDE, j = idx % HDE;
    float s = b1[j];
    for (int d = 0; d < IBn; ++d) s = fmaf(z[b * IBn + d], w1[d * HDE + j], s);
    s = s * (gamma[j] / sqrtf(1.0f + 1e-5f)) + beta[j];
    h[idx] = fmaxf(s, 0.0f);
}

// ---------------- decoder layer 2 ----------------
__global__ void dec2_k(const float* __restrict__ h, const float* __restrict__ w2,
                       const float* __restrict__ b2, float* __restrict__ out)
{
    const int idx = blockIdx.x * 256 + threadIdx.x;
    if (idx >= Bn * Nn) return;
    const int b = idx / Nn, n = idx % Nn;
    float s = b2[n];
    for (int j = 0; j < HDE; ++j) s = fmaf(h[b * HDE + j], w2[(long long)j * Nn + n], s);
    out[idx] = fmaxf(s, 0.0f);
}

// ---------------- host ----------------
extern "C" void kernel_launch(void* const* d_in, const int* in_sizes, int n_in,
                              void* d_out, int out_size, void* d_ws, size_t ws_size,
                              hipStream_t stream)
{
    const float* x1     = (const float*)d_in[0];
    const float* x2     = (const float*)d_in[1];
    const float* emb1   = (const float*)d_in[2];
    const float* gate_w = (const float*)d_in[3];
    const float* gate_b = (const float*)d_in[4];
    const float* enc_w1 = (const float*)d_in[5];
    const float* enc_b1 = (const float*)d_in[6];
    const float* enc_w2 = (const float*)d_in[7];
    const float* enc_b2 = (const float*)d_in[8];
    const float* gl_w   = (const float*)d_in[9];
    const float* g_w1   = (const float*)d_in[10];
    const float* g_b1   = (const float*)d_in[11];
    const float* g_w2   = (const float*)d_in[12];
    const float* g_b2   = (const float*)d_in[13];
    const float* g_w3   = (const float*)d_in[14];
    const float* g_b3   = (const float*)d_in[15];
    const float* dec_w1[2] = {(const float*)d_in[16], (const float*)d_in[22]};
    const float* dec_b1[2] = {(const float*)d_in[17], (const float*)d_in[23]};
    const float* dec_g [2] = {(const float*)d_in[18], (const float*)d_in[24]};
    const float* dec_be[2] = {(const float*)d_in[19], (const float*)d_in[25]};
    const float* dec_w2[2] = {(const float*)d_in[20], (const float*)d_in[26]};
    const float* dec_b2[2] = {(const float*)d_in[21], (const float*)d_in[27]};
    const float* epsv  [2] = {(const float*)d_in[28], (const float*)d_in[29]};
    const float* xv    [2] = {x1, x2};

    float* ws = (float*)d_ws;
    // workspace layout (floats); total ~50.5M floats ~= 202 MB
    const long long ATT   = 0;                         // 32,000,000 (B*N*N); first 8.2M doubles as gate-X
    const long long HBUF  = ATT + (long long)Bn * Nn * Nn;       // 2,048,000
    const long long BUFA  = HBUF + (long long)Bn * Nn * Dn;      // 8,192,000 ; BUFA..BUFB also hosts henc (16.4M)
    const long long BUFB  = BUFA + (long long)Bn * Nn * HDn;     // 8,192,000
    const long long DINV  = BUFB + (long long)Bn * Nn * HDn;     // 16,000
    const long long GMEAN = DINV + (long long)Bn * Nn;           // 1,024
    const long long ZBUF  = GMEAN + Bn * Dn;                     // 512
    const long long HDECO = ZBUF + Bn * IBn;                     // 8,192

    float* att   = ws + ATT;
    float* Xg    = ws + ATT;     // (16000,512) gate output, dead before att is written
    float* Hbuf  = ws + HBUF;    // (16000,128)
    float* bufA  = ws + BUFA;    // (16000,512)
    float* bufB  = ws + BUFB;    // (16000,512)
    float* henc  = ws + BUFA;    // (16000,1024) spans bufA+bufB, dead before GCN
    float* dinv  = ws + DINV;
    float* gmean = ws + GMEAN;
    float* zbuf  = ws + ZBUF;
    float* hdec  = ws + HDECO;

    const int MBN = Bn * Nn;     // 16000
    const long long sAtt = (long long)Nn * Nn;      // 4,000,000
    const long long sF   = (long long)Nn * HDn;     // 1,024,000
    const long long sD   = (long long)Nn * Dn;      //   256,000

    for (int g = 0; g < 2; ++g) {
        float* xrec_out = (float*)d_out + g * MBN;
        float* mu_out   = (float*)d_out + 2 * MBN + g * 2 * Bn * IBn;
        float* std_out  = mu_out + Bn * IBn;

        // ---- encoder ----
        gate_k<<<CDIV((long long)MBN * En, 256), 256, 0, stream>>>(xv[g], gate_w, gate_b, emb1, Xg);
        gemm_k<2, false, false, false, false><<<dim3(CDIV(MBN, BM), CDIV(HEN, BN), 1), 256, 0, stream>>>(
            Xg, enc_w1, enc_b1, henc, MBN, HEN, En, 0, 0, 0);
        gemm_k<0, false, false, false, false><<<dim3(CDIV(MBN, BM), CDIV(Dn, BN), 1), 256, 0, stream>>>(
            henc, enc_w2, enc_b2, Hbuf, MBN, Dn, HEN, 0, 0, 0);

        // ---- learned adjacency: att = (1/P) sum_p relu(H gl_w[p]) relu(H gl_w[p])^T ----
        for (int p = 0; p < Pn; ++p) {
            gemm_k<1, false, false, false, false><<<dim3(CDIV(MBN, BM), CDIV(HDn, BN), 1), 256, 0, stream>>>(
                Hbuf, gl_w + (long long)p * Dn * HDn, nullptr, bufA, MBN, HDn, Dn, 0, 0, 0);
            if (p == 0)
                gemm_k<0, false, true, false, true><<<dim3(CDIV(Nn, BM), CDIV(Nn, BN), Bn), 256, 0, stream>>>(
                    bufA, bufA, nullptr, att, Nn, Nn, HDn, sF, sF, sAtt);
            else
                gemm_k<0, false, true, true, true><<<dim3(CDIV(Nn, BM), CDIV(Nn, BN), Bn), 256, 0, stream>>>(
                    bufA, bufA, nullptr, att, Nn, Nn, HDn, sF, sF, sAtt);
        }
        mirror_k<<<dim3(CDIV(Nn, 64), CDIV(Nn, 64), Bn), 256, 0, stream>>>(att);
        topk_softmax_k<<<MBN, 256, 0, stream>>>(att);

        // ---- GCN normalization ----
        colsum_k<<<dim3(CDIV(Nn, 256), Bn, 1), 256, 0, stream>>>(att, dinv);
        norm_adj_k<<<dim3(CDIV(Nn, 256), Nn, Bn), 256, 0, stream>>>(att, dinv);

        // ---- GCN layers: out = An^T (z @ w) + b ----
        gemm_k<0, false, false, false, false><<<dim3(CDIV(MBN, BM), CDIV(HDn, BN), 1), 256, 0, stream>>>(
            Hbuf, g_w1, nullptr, bufA, MBN, HDn, Dn, 0, 0, 0);
        gemm_k<1, true, false, false, false><<<dim3(CDIV(Nn, BM), CDIV(HDn, BN), Bn), 256, 0, stream>>>(
            att, bufA, g_b1, bufB, Nn, HDn, Nn, sAtt, sF, sF);
        gemm_k<0, false, false, false, false><<<dim3(CDIV(MBN, BM), CDIV(HDn, BN), 1), 256, 0, stream>>>(
            bufB, g_w2, nullptr, bufA, MBN, HDn, HDn, 0, 0, 0);
        gemm_k<1, true, false, false, false><<<dim3(CDIV(Nn, BM), CDIV(HDn, BN), Bn), 256, 0, stream>>>(
            att, bufA, g_b2, bufB, Nn, HDn, Nn, sAtt, sF, sF);
        gemm_k<0, false, false, false, false><<<dim3(CDIV(MBN, BM), CDIV(Dn, BN), 1), 256, 0, stream>>>(
            bufB, g_w3, nullptr, bufA, MBN, Dn, HDn, 0, 0, 0);
        gemm_k<0, true, false, false, false><<<dim3(CDIV(Nn, BM), CDIV(Dn, BN), Bn), 256, 0, stream>>>(
            att, bufA, g_b3, Hbuf, Nn, Dn, Nn, sAtt, sD, sD);

        // ---- readout + VIB + decoder ----
        mean_k<<<Bn, Dn, 0, stream>>>(Hbuf, gmean);
        vib_k<<<CDIV(Bn * IBn, 256), 256, 0, stream>>>(gmean, epsv[g], mu_out, std_out, zbuf);
        dec1_k<<<CDIV(Bn * HDE, 256), 256, 0, stream>>>(zbuf, dec_w1[g], dec_b1[g], dec_g[g], dec_be[g], hdec);
        dec2_k<<<CDIV(Bn * Nn, 256), 256, 0, stream>>>(hdec, dec_w2[g], dec_b2[g], xrec_out);
    }
}

// Round 2
// 4198.311 us; speedup vs baseline: 4.6073x; 4.6073x over previous
//
#include <hip/hip_runtime.h>
#include <hip/hip_bf16.h>
#include <math.h>

#define CDIV(a,b) (((a)+(b)-1)/(b))

// ---------------- problem constants ----------------
#define Bn   8
#define Nn   2000
#define En   512
#define HEN  1024
#define Dn   128
#define HDn  512
#define Pn   8
#define HDE  1024
#define IBn  64
#define TOPK 50

typedef __attribute__((ext_vector_type(8))) short bf16x8;
typedef __attribute__((ext_vector_type(4))) float f32x4;

__device__ __forceinline__ float gelu_exact(float x) {
    return 0.5f * x * (1.0f + erff(x * 0.70710678118654752440f));
}
__device__ __forceinline__ ushort f2b(float f) {          // fp32 -> bf16 RNE
    unsigned u = __float_as_uint(f);
    unsigned r = u + 0x7FFFu + ((u >> 16) & 1u);
    return (ushort)(r >> 16);
}
__device__ __forceinline__ float ld_as_f(const float* p)  { return *p; }
__device__ __forceinline__ float ld_as_f(const ushort* p) { return __uint_as_float(((unsigned)*p) << 16); }

// ================= MFMA bf16 GEMM =================
// C[M,N] = act( sum_k A[m,k] * B[n,k] + bias[n] )  (A:(M,K) bf16, B:(N,K) bf16)
// batched via element strides sA/sB/sC. OUT_BF16: store bf16, else fp32 (opt ACCUM).
// UPPER: skip tiles with bx > by (symmetric C; mirror_k fills lower).
#define GBM 128
#define GBN 128
#define GBK 64
#define LDP 72   // padded LDS row length (ushorts); 144B stride -> 2-way max bank alias (free)

template<int ACT, bool ACCUM, bool UPPER, bool OUT_BF16>
__global__ __launch_bounds__(256) void mgemm_k(
    const ushort* __restrict__ A, const ushort* __restrict__ B,
    const float* __restrict__ bias, void* __restrict__ Cv,
    int M, int N, int K,
    long long sA, long long sB, long long sC)
{
    if (UPPER && blockIdx.x > blockIdx.y) return;
    const int bz = blockIdx.z;
    const ushort* Ab = A + (long long)bz * sA;
    const ushort* Bb = B + (long long)bz * sB;
    const int bm0 = blockIdx.x * GBM;
    const int bn0 = blockIdx.y * GBN;

    __shared__ __align__(16) ushort As[GBM * LDP];
    __shared__ __align__(16) ushort Bs[GBN * LDP];

    const int tid  = threadIdx.x;
    const int lane = tid & 63;
    const int w    = tid >> 6;           // wave 0..3
    const int wm   = (w >> 1) * 64;      // wave M offset in tile
    const int wn   = (w & 1) * 64;       // wave N offset in tile
    const int lr   = lane & 15;          // fragment row/col
    const int lk   = (lane >> 4) * 8;    // fragment k-offset within 32

    const int stg_k = (tid & 7) * 8;     // staging k-offset (8 bf16 = 16B)
    const int stg_r = tid >> 3;          // staging row 0..31 (x4 passes)

    f32x4 acc[4][4];
#pragma unroll
    for (int i = 0; i < 4; ++i)
#pragma unroll
        for (int j = 0; j < 4; ++j) acc[i][j] = {0.f, 0.f, 0.f, 0.f};

    const int nK = (K + GBK - 1) / GBK;   // all K used are multiples of 8
    for (int kt = 0; kt < nK; ++kt) {
        const int k0 = kt * GBK;
        const int gk = k0 + stg_k;
        const bool kok = (gk < K);
#pragma unroll
        for (int pass = 0; pass < 4; ++pass) {
            const int r = pass * 32 + stg_r;
            uint4 va = {0u, 0u, 0u, 0u};
            const int gmA = bm0 + r;
            if (kok && gmA < M) va = *(const uint4*)(Ab + (long long)gmA * K + gk);
            *(uint4*)(&As[r * LDP + stg_k]) = va;
            uint4 vb = {0u, 0u, 0u, 0u};
            const int gnB = bn0 + r;
            if (kok && gnB < N) vb = *(const uint4*)(Bb + (long long)gnB * K + gk);
            *(uint4*)(&Bs[r * LDP + stg_k]) = vb;
        }
        __syncthreads();
#pragma unroll
        for (int kk = 0; kk < 2; ++kk) {
            bf16x8 af[4], bfr[4];
#pragma unroll
            for (int i = 0; i < 4; ++i)
                af[i] = *(const bf16x8*)(&As[(wm + i * 16 + lr) * LDP + kk * 32 + lk]);
#pragma unroll
            for (int j = 0; j < 4; ++j)
                bfr[j] = *(const bf16x8*)(&Bs[(wn + j * 16 + lr) * LDP + kk * 32 + lk]);
#pragma unroll
            for (int i = 0; i < 4; ++i)
#pragma unroll
                for (int j = 0; j < 4; ++j)
                    acc[i][j] = __builtin_amdgcn_mfma_f32_16x16x32_bf16(af[i], bfr[j], acc[i][j], 0, 0, 0);
        }
        __syncthreads();
    }

    // epilogue: C/D layout col = lane&15, row = (lane>>4)*4 + reg  [m89-verified]
    const int crow = (lane >> 4) * 4;
    const int ccol = lane & 15;
#pragma unroll
    for (int i = 0; i < 4; ++i) {
#pragma unroll
        for (int j = 0; j < 4; ++j) {
            const int gn = bn0 + wn + j * 16 + ccol;
            if (gn >= N) continue;
            const float bv = bias ? bias[gn] : 0.0f;
#pragma unroll
            for (int rr = 0; rr < 4; ++rr) {
                const int gm = bm0 + wm + i * 16 + crow + rr;
                if (gm >= M) continue;
                float v = acc[i][j][rr] + bv;
                if (ACT == 1) v = fmaxf(v, 0.0f);
                if (ACT == 2) v = gelu_exact(v);
                const long long idx = (long long)bz * sC + (long long)gm * N + gn;
                if (OUT_BF16) {
                    ((ushort*)Cv)[idx] = f2b(v);
                } else {
                    float* Cf = (float*)Cv;
                    if (ACCUM) Cf[idx] += v; else Cf[idx] = v;
                }
            }
        }
    }
}

// ============ transpose (+convert) to bf16, batched ============
// out[z][c][r] = (bf16) in[z][r][c]
template<typename T>
__global__ __launch_bounds__(256) void transpose_bf16_k(
    const T* __restrict__ in, ushort* __restrict__ out, int R, int C)
{
    __shared__ float tile[32][33];
    const long long base = (long long)blockIdx.z * R * C;
    const int r0 = blockIdx.y * 32, c0 = blockIdx.x * 32;
    const int tx = threadIdx.x & 31, ty = threadIdx.x >> 5;   // 32x8
    for (int i = ty; i < 32; i += 8) {
        const int r = r0 + i, c = c0 + tx;
        float v = 0.0f;
        if (r < R && c < C) v = ld_as_f(in + base + (long long)r * C + c);
        tile[i][tx] = v;
    }
    __syncthreads();
    for (int i = ty; i < 32; i += 8) {
        const int c = c0 + i, r = r0 + tx;
        if (c < C && r < R) out[base + (long long)c * R + r] = f2b(tile[tx][i]);
    }
}

// ---------------- gate * emb -> bf16 ----------------
__global__ void gate_k(const float* __restrict__ x, const float* __restrict__ gw,
                       const float* __restrict__ gb, const float* __restrict__ emb,
                       ushort* __restrict__ X)
{
    const long long total = (long long)Bn * Nn * En;
    const long long idx = (long long)blockIdx.x * 256 + threadIdx.x;
    if (idx >= total) return;
    const int e = (int)(idx % En);
    const long long bn = idx / En;
    const int n = (int)(bn % Nn);
    const float t = x[bn] * gw[e] + gb[e];
    const float s = 1.0f / (1.0f + expf(-t));
    X[idx] = f2b(s * emb[(long long)n * En + e]);
}

// ---------------- mirror: lower blocks <- transpose(upper) ----------------
__global__ __launch_bounds__(256) void mirror_k(float* __restrict__ att)
{
    const int bi = blockIdx.x, bj = blockIdx.y;
    if (bi <= bj) return;
    float* A = att + (long long)blockIdx.z * Nn * Nn;
    __shared__ float t64[64][65];
    const int ti = threadIdx.x & 63;
    const int tj = threadIdx.x >> 6;
    const int i0 = bi * 64, j0 = bj * 64;
    for (int r = tj; r < 64; r += 4) {
        const int sr = j0 + r, sc = i0 + ti;
        t64[r][ti] = (sr < Nn && sc < Nn) ? A[(long long)sr * Nn + sc] : 0.0f;
    }
    __syncthreads();
    for (int r = tj; r < 64; r += 4) {
        const int dr = i0 + r, dc = j0 + ti;
        if (dr < Nn && dc < Nn) A[(long long)dr * Nn + dc] = t64[ti][r];
    }
}

// ---------------- top-k threshold + masked softmax (per row) ----------------
__global__ __launch_bounds__(256) void topk_softmax_k(float* __restrict__ att)
{
    const long long row = blockIdx.x;
    float* r = att + row * Nn;
    __shared__ float vals[Nn];
    __shared__ unsigned hist[256];
    __shared__ float red[256];
    __shared__ unsigned sel_prefix;
    __shared__ int sel_k;
    const int t = threadIdx.x;

    for (int j = t; j < Nn; j += 256) vals[j] = r[j] * 0.125f;   // att / P
    __syncthreads();

    unsigned prefix = 0;
    int kneed = TOPK;
    for (int shift = 24; shift >= 0; shift -= 8) {
        hist[t] = 0;
        __syncthreads();
        const unsigned pmask = (shift == 24) ? 0u : (0xFFFFFFFFu << (shift + 8));
        for (int j = t; j < Nn; j += 256) {
            const unsigned u = __float_as_uint(vals[j]);
            if ((u & pmask) == prefix) atomicAdd(&hist[(u >> shift) & 255u], 1u);
        }
        __syncthreads();
        if (t == 0) {
            int acc = 0, b = 255;
            for (; b >= 0; --b) {
                const int c = (int)hist[b];
                if (acc + c >= kneed) break;
                acc += c;
            }
            if (b < 0) b = 0;
            sel_prefix = prefix | ((unsigned)b << shift);
            sel_k = kneed - acc;
        }
        __syncthreads();
        prefix = sel_prefix;
        kneed = sel_k;
        __syncthreads();
    }
    const float thr = __uint_as_float(prefix);

    float lm = -1e30f;
    for (int j = t; j < Nn; j += 256) lm = fmaxf(lm, vals[j]);
    red[t] = lm; __syncthreads();
    for (int s = 128; s > 0; s >>= 1) { if (t < s) red[t] = fmaxf(red[t], red[t + s]); __syncthreads(); }
    const float rowmax = red[0]; __syncthreads();

    float ls = 0.0f;
    for (int j = t; j < Nn; j += 256)
        if (vals[j] >= thr) ls += expf(vals[j] - rowmax);
    red[t] = ls; __syncthreads();
    for (int s = 128; s > 0; s >>= 1) { if (t < s) red[t] += red[t + s]; __syncthreads(); }
    const float Z = red[0]; __syncthreads();

    for (int j = t; j < Nn; j += 256) {
        const float v = vals[j];
        r[j] = (v >= thr) ? (expf(v - rowmax) / Z) : 0.0f;
    }
}

// ---------------- column sums of (adj + I) -> rsqrt ----------------
__global__ void colsum_k(const float* __restrict__ att, float* __restrict__ dinv)
{
    const int b = blockIdx.y;
    const int i = blockIdx.x * 256 + threadIdx.x;
    if (i >= Nn) return;
    const float* A = att + (long long)b * Nn * Nn;
    float s = 1.0f;
    for (int j = 0; j < Nn; ++j) s += A[(long long)j * Nn + i];
    dinv[b * Nn + i] = rsqrtf(s);
}

// ---------------- An[j][i] = (adj[j][i] + (i==j)) * dinv[j]*dinv[i] ----------------
__global__ void norm_adj_k(float* __restrict__ att, const float* __restrict__ dinv)
{
    const int i = blockIdx.x * 256 + threadIdx.x;
    if (i >= Nn) return;
    const int j = blockIdx.y;
    const int b = blockIdx.z;
    const long long off = ((long long)b * Nn + j) * Nn + i;
    float v = att[off] + ((i == j) ? 1.0f : 0.0f);
    att[off] = v * dinv[b * Nn + j] * dinv[b * Nn + i];
}

// ---------------- mean over nodes ----------------
__global__ void mean_k(const float* __restrict__ nout, float* __restrict__ g)
{
    const int b = blockIdx.x;
    const int d = threadIdx.x;                    // Dn = 128 threads
    float s = 0.0f;
    for (int i = 0; i < Nn; ++i) s += nout[((long long)b * Nn + i) * Dn + d];
    g[b * Dn + d] = s / (float)Nn;
}

// ---------------- VIB head ----------------
__global__ void vib_k(const float* __restrict__ g, const float* __restrict__ eps,
                      float* __restrict__ mu_out, float* __restrict__ std_out,
                      float* __restrict__ z)
{
    const int t = blockIdx.x * 256 + threadIdx.x;
    if (t >= Bn * IBn) return;
    const int b = t / IBn, d = t % IBn;
    const float mu = g[b * Dn + d];
    const float x = g[b * Dn + IBn + d] - (float)IBn;
    const float sp = (x > 0.0f) ? (x + log1pf(expf(-x))) : log1pf(expf(x));
    mu_out[t] = mu;
    std_out[t] = sp;
    z[t] = mu + eps[t] * sp;
}

// ---------------- decoder layers (fp32, tiny) ----------------
__global__ void dec1_k(const float* __restrict__ z, const float* __restrict__ w1,
                       const float* __restrict__ b1, const float* __restrict__ gamma,
                       const float* __restrict__ beta, float* __restrict__ h)
{
    const int idx = blockIdx.x * 256 + threadIdx.x;
    if (idx >= Bn * HDE) return;
    const int b = idx / HDE, j = idx % HDE;
    float s = b1[j];
    for (int d = 0; d < IBn; ++d) s = fmaf(z[b * IBn + d], w1[d * HDE + j], s);
    s = s * (gamma[j] / sqrtf(1.0f + 1e-5f)) + beta[j];
    h[idx] = fmaxf(s, 0.0f);
}

__global__ void dec2_k(const float* __restrict__ h, const float* __restrict__ w2,
                       const float* __restrict__ b2, float* __restrict__ out)
{
    const int idx = blockIdx.x * 256 + threadIdx.x;
    if (idx >= Bn * Nn) return;
    const int b = idx / Nn, n = idx % Nn;
    float s = b2[n];
    for (int j = 0; j < HDE; ++j) s = fmaf(h[b * HDE + j], w2[(long long)j * Nn + n], s);
    out[idx] = fmaxf(s, 0.0f);
}

// ---------------- host ----------------
extern "C" void kernel_launch(void* const* d_in, const int* in_sizes, int n_in,
                              void* d_out, int out_size, void* d_ws, size_t ws_size,
                              hipStream_t stream)
{
    const float* x1     = (const float*)d_in[0];
    const float* x2     = (const float*)d_in[1];
    const float* emb1   = (const float*)d_in[2];
    const float* gate_w = (const float*)d_in[3];
    const float* gate_b = (const float*)d_in[4];
    const float* enc_w1 = (const float*)d_in[5];
    const float* enc_b1 = (const float*)d_in[6];
    const float* enc_w2 = (const float*)d_in[7];
    const float* enc_b2 = (const float*)d_in[8];
    const float* gl_w   = (const float*)d_in[9];
    const float* g_w1   = (const float*)d_in[10];
    const float* g_b1   = (const float*)d_in[11];
    const float* g_w2   = (const float*)d_in[12];
    const float* g_b2   = (const float*)d_in[13];
    const float* g_w3   = (const float*)d_in[14];
    const float* g_b3   = (const float*)d_in[15];
    const float* dec_w1[2] = {(const float*)d_in[16], (const float*)d_in[22]};
    const float* dec_b1[2] = {(const float*)d_in[17], (const float*)d_in[23]};
    const float* dec_g [2] = {(const float*)d_in[18], (const float*)d_in[24]};
    const float* dec_be[2] = {(const float*)d_in[19], (const float*)d_in[25]};
    const float* dec_w2[2] = {(const float*)d_in[20], (const float*)d_in[26]};
    const float* dec_b2[2] = {(const float*)d_in[21], (const float*)d_in[27]};
    const float* epsv  [2] = {(const float*)d_in[28], (const float*)d_in[29]};
    const float* xv    [2] = {x1, x2};

    char* W = (char*)d_ws;
    const int MBN = Bn * Nn;  // 16000

    // ---- workspace layout (bytes), total ~200.9 MB ----
    // R0 [0, 128MB): att fp32; early aliases Xg/henc; late aliases ZW/ZWT/bufB/Hout
    float*  att  = (float*) (W + 0);
    ushort* Xg   = (ushort*)(W + 0);                     // 16,384,000 (dead before att)
    ushort* henc = (ushort*)(W + 16384000);              // 32,768,000 (dead before att)
    ushort* ZW   = (ushort*)(W + 0);                     // 16,384,000 (att dead by then)
    ushort* ZWT  = (ushort*)(W + 16384000);              // 16,384,000
    ushort* bufB = (ushort*)(W + 32768000);              // 16,384,000
    float*  Hout = (float*) (W + 49152000);              //  8,192,000
    // R1 [128MB, 193.5MB): F2 bf16 (16000x2048); later attT bf16 (8x2000x2000)
    ushort* F2   = (ushort*)(W + 128000000);             // 65,536,000
    ushort* attT = (ushort*)(W + 128000000);             // 64,000,000 (F2 dead)
    // R2 [193.5MB, ...): persistent small buffers
    ushort* Hb     = (ushort*)(W + 193536000);           // 4,096,000  (16000x128 bf16)
    ushort* enc_w1T= (ushort*)(W + 197632000);           // (1024,512)
    ushort* enc_w2T= (ushort*)(W + 198680576);           // (128,1024)
    ushort* glT    = (ushort*)(W + 198942720);           // (4096,128) = batched (8,512,128)
    ushort* g_w1T  = (ushort*)(W + 199991296);           // (512,128)
    ushort* g_w2T  = (ushort*)(W + 200122368);           // (512,512)
    ushort* g_w3T  = (ushort*)(W + 200646656);           // (128,512)
    float*  dinv   = (float*) (W + 200777728);           // 16000
    float*  gmean  = (float*) (W + 200841728);           // 8x128
    float*  zbuf   = (float*) (W + 200845824);           // 8x64
    float*  hdec   = (float*) (W + 200847872);           // 8x1024

    const long long sAtt  = (long long)Nn * Nn;          // 4,000,000
    const long long sF2   = (long long)Nn * 2048;        // per-batch stride in F2
    const long long sZWT  = (long long)HDn * Nn;         // 1,024,000
    const long long sBufB = (long long)Nn * HDn;         // 1,024,000
    const long long sZT3  = (long long)Dn * Nn;          //   256,000
    const long long sHout = (long long)Nn * Dn;          //   256,000

    // ---- weight prep (cheap; once per launch) ----
    transpose_bf16_k<float><<<dim3(CDIV(HEN,32), CDIV(En,32), 1), 256, 0, stream>>>(enc_w1, enc_w1T, En, HEN);
    transpose_bf16_k<float><<<dim3(CDIV(Dn,32),  CDIV(HEN,32),1), 256, 0, stream>>>(enc_w2, enc_w2T, HEN, Dn);
    transpose_bf16_k<float><<<dim3(CDIV(HDn,32), CDIV(Dn,32), Pn),256, 0, stream>>>(gl_w,   glT,     Dn,  HDn);
    transpose_bf16_k<float><<<dim3(CDIV(HDn,32), CDIV(Dn,32), 1), 256, 0, stream>>>(g_w1,   g_w1T,   Dn,  HDn);
    transpose_bf16_k<float><<<dim3(CDIV(HDn,32), CDIV(HDn,32),1), 256, 0, stream>>>(g_w2,   g_w2T,   HDn, HDn);
    transpose_bf16_k<float><<<dim3(CDIV(Dn,32),  CDIV(HDn,32),1), 256, 0, stream>>>(g_w3,   g_w3T,   HDn, Dn);

    for (int g = 0; g < 2; ++g) {
        float* xrec_out = (float*)d_out + g * MBN;
        float* mu_out   = (float*)d_out + 2 * MBN + g * 2 * Bn * IBn;
        float* std_out  = mu_out + Bn * IBn;

        // ---- encoder ----
        gate_k<<<CDIV((long long)MBN * En, 256), 256, 0, stream>>>(xv[g], gate_w, gate_b, emb1, Xg);
        mgemm_k<2,false,false,true><<<dim3(CDIV(MBN,GBM), CDIV(HEN,GBN), 1), 256, 0, stream>>>(
            Xg, enc_w1T, enc_b1, henc, MBN, HEN, En, 0, 0, 0);
        mgemm_k<0,false,false,true><<<dim3(CDIV(MBN,GBM), CDIV(Dn,GBN), 1), 256, 0, stream>>>(
            henc, enc_w2T, enc_b2, Hb, MBN, Dn, HEN, 0, 0, 0);

        // ---- adjacency: att = sum_p relu(H gl_w[p]) relu(H gl_w[p])^T (2 concat-K groups) ----
        for (int g2 = 0; g2 < 2; ++g2) {
            mgemm_k<1,false,false,true><<<dim3(CDIV(MBN,GBM), CDIV(2048,GBN), 1), 256, 0, stream>>>(
                Hb, glT + (long long)g2 * 2048 * Dn, nullptr, F2, MBN, 2048, Dn, 0, 0, 0);
            if (g2 == 0)
                mgemm_k<0,false,true,false><<<dim3(CDIV(Nn,GBM), CDIV(Nn,GBN), Bn), 256, 0, stream>>>(
                    F2, F2, nullptr, att, Nn, Nn, 2048, sF2, sF2, sAtt);
            else
                mgemm_k<0,true,true,false><<<dim3(CDIV(Nn,GBM), CDIV(Nn,GBN), Bn), 256, 0, stream>>>(
                    F2, F2, nullptr, att, Nn, Nn, 2048, sF2, sF2, sAtt);
        }
        mirror_k<<<dim3(CDIV(Nn,64), CDIV(Nn,64), Bn), 256, 0, stream>>>(att);
        topk_softmax_k<<<MBN, 256, 0, stream>>>(att);

        // ---- GCN normalization ----
        colsum_k<<<dim3(CDIV(Nn,256), Bn, 1), 256, 0, stream>>>(att, dinv);
        norm_adj_k<<<dim3(CDIV(Nn,256), Nn, Bn), 256, 0, stream>>>(att, dinv);
        // An^T as bf16: attT[b][i][j] = An[b][j][i]
        transpose_bf16_k<float><<<dim3(CDIV(Nn,32), CDIV(Nn,32), Bn), 256, 0, stream>>>(att, attT, Nn, Nn);

        // ---- GCN layer 1 ----
        mgemm_k<0,false,false,true><<<dim3(CDIV(MBN,GBM), CDIV(HDn,GBN), 1), 256, 0, stream>>>(
            Hb, g_w1T, nullptr, ZW, MBN, HDn, Dn, 0, 0, 0);
        transpose_bf16_k<ushort><<<dim3(CDIV(HDn,32), CDIV(Nn,32), Bn), 256, 0, stream>>>(ZW, ZWT, Nn, HDn);
        mgemm_k<1,false,false,true><<<dim3(CDIV(Nn,GBM), CDIV(HDn,GBN), Bn), 256, 0, stream>>>(
            attT, ZWT, g_b1, bufB, Nn, HDn, Nn, sAtt, sZWT, sBufB);
        // ---- GCN layer 2 ----
        mgemm_k<0,false,false,true><<<dim3(CDIV(MBN,GBM), CDIV(HDn,GBN), 1), 256, 0, stream>>>(
            bufB, g_w2T, nullptr, ZW, MBN, HDn, HDn, 0, 0, 0);
        transpose_bf16_k<ushort><<<dim3(CDIV(HDn,32), CDIV(Nn,32), Bn), 256, 0, stream>>>(ZW, ZWT, Nn, HDn);
        mgemm_k<1,false,false,true><<<dim3(CDIV(Nn,GBM), CDIV(HDn,GBN), Bn), 256, 0, stream>>>(
            attT, ZWT, g_b2, bufB, Nn, HDn, Nn, sAtt, sZWT, sBufB);
        // ---- GCN layer 3 ----
        mgemm_k<0,false,false,true><<<dim3(CDIV(MBN,GBM), CDIV(Dn,GBN), 1), 256, 0, stream>>>(
            bufB, g_w3T, nullptr, ZW, MBN, Dn, HDn, 0, 0, 0);
        transpose_bf16_k<ushort><<<dim3(CDIV(Dn,32), CDIV(Nn,32), Bn), 256, 0, stream>>>(ZW, ZWT, Nn, Dn);
        mgemm_k<0,false,false,false><<<dim3(CDIV(Nn,GBM), CDIV(Dn,GBN), Bn), 256, 0, stream>>>(
            attT, ZWT, g_b3, Hout, Nn, Dn, Nn, sAtt, sZT3, sHout);

        // ---- readout + VIB + decoder ----
        mean_k<<<Bn, Dn, 0, stream>>>(Hout, gmean);
        vib_k<<<CDIV(Bn * IBn, 256), 256, 0, stream>>>(gmean, epsv[g], mu_out, std_out, zbuf);
        dec1_k<<<CDIV(Bn * HDE, 256), 256, 0, stream>>>(zbuf, dec_w1[g], dec_b1[g], dec_g[g], dec_be[g], hdec);
        dec2_k<<<CDIV(Bn * Nn, 256), 256, 0, stream>>>(hdec, dec_w2[g], dec_b2[g], xrec_out);
    }
}

// Round 3
// 2526.927 us; speedup vs baseline: 7.6548x; 1.6614x over previous
//
#include <hip/hip_runtime.h>
#include <hip/hip_bf16.h>
#include <math.h>

#define CDIV(a,b) (((a)+(b)-1)/(b))

// ---------------- problem constants ----------------
#define Bn   8
#define Nn   2000
#define NnP  2048      // Nn padded to K-multiple of 64 (zero-filled)
#define En   512
#define HEN  1024
#define Dn   128
#define HDn  512
#define Pn   8
#define HDE  1024
#define IBn  64
#define TOPK 50

typedef __attribute__((ext_vector_type(8))) short bf16x8;
typedef __attribute__((ext_vector_type(4))) float f32x4;

__device__ __forceinline__ float gelu_exact(float x) {
    return 0.5f * x * (1.0f + erff(x * 0.70710678118654752440f));
}
__device__ __forceinline__ ushort f2b(float f) {          // fp32 -> bf16 RNE
    unsigned u = __float_as_uint(f);
    unsigned r = u + 0x7FFFu + ((u >> 16) & 1u);
    return (ushort)(r >> 16);
}
__device__ __forceinline__ float ld_as_f(const float* p)  { return *p; }
__device__ __forceinline__ float ld_as_f(const ushort* p) { return __uint_as_float(((unsigned)*p) << 16); }

__device__ __forceinline__ void gload16(const ushort* g, ushort* l) {
    // async global->LDS, 16B per lane; LDS dest wave-uniform base + lane*16
    __builtin_amdgcn_global_load_lds(
        (const __attribute__((address_space(1))) unsigned int*)(const void*)g,
        (__attribute__((address_space(3))) unsigned int*)(void*)l, 16, 0, 0);
}

// ================= MFMA bf16 GEMM (global_load_lds + XOR swizzle) =================
// C[M,N] = act( sum_k A[m,k]*B[n,k] + bias[n] ),  A:(M,K) bf16, B:(N,K) bf16, K % 64 == 0.
// LDS[r][c] = G[r][c ^ (r&7)] (16B chunks): source chunk (lane&7)^(lane>>3) is linear-written
// by global_load_lds; ds_read applies the same XOR -> conflict-free b128 reads.
#define GBM 128
#define GBN 128
#define GBK 64

template<int ACT, bool ACCUM, bool UPPER, bool OUT_BF16>
__global__ __launch_bounds__(256) void mgemm_k(
    const ushort* __restrict__ A, const ushort* __restrict__ B,
    const float* __restrict__ bias, void* __restrict__ Cv,
    int M, int N, int K,
    long long sA, long long sB, long long sC)
{
    if (UPPER && blockIdx.x > blockIdx.y) return;
    const int bz = blockIdx.z;
    const ushort* Ab = A + (long long)bz * sA;
    const ushort* Bb = B + (long long)bz * sB;
    const int bm0 = blockIdx.x * GBM;
    const int bn0 = blockIdx.y * GBN;

    __shared__ __align__(16) ushort As[GBM * GBK];
    __shared__ __align__(16) ushort Bs[GBN * GBK];

    const int tid  = threadIdx.x;
    const int lane = tid & 63;
    const int w    = tid >> 6;           // wave 0..3
    const int wm   = (w >> 1) * 64;
    const int wn   = (w & 1) * 64;
    const int lr   = lane & 15;
    const int hi   = lane >> 4;          // 0..3

    const int srow = lane >> 3;          // 0..7 (row within 8-row staging chunk)
    const int sch  = (lane & 7) ^ srow;  // inverse-swizzled source 16B-chunk

    f32x4 acc[4][4];
#pragma unroll
    for (int i = 0; i < 4; ++i)
#pragma unroll
        for (int j = 0; j < 4; ++j) acc[i][j] = {0.f, 0.f, 0.f, 0.f};

    const int nK = K / GBK;
    for (int kt = 0; kt < nK; ++kt) {
        const int k0 = kt * GBK;
#pragma unroll
        for (int i = 0; i < 4; ++i) {
            const int r = w * 32 + i * 8 + srow;
            int gm = bm0 + r; if (gm > M - 1) gm = M - 1;   // clamp; masked at epilogue
            gload16(Ab + (long long)gm * K + k0 + sch * 8, &As[(w * 32 + i * 8) * GBK]);
            int gn = bn0 + r; if (gn > N - 1) gn = N - 1;
            gload16(Bb + (long long)gn * K + k0 + sch * 8, &Bs[(w * 32 + i * 8) * GBK]);
        }
        __syncthreads();
#pragma unroll
        for (int kk = 0; kk < 2; ++kk) {
            bf16x8 af[4], bfr[4];
#pragma unroll
            for (int i = 0; i < 4; ++i) {
                const int r = wm + i * 16 + lr;
                af[i] = *(const bf16x8*)(&As[r * GBK + (((kk * 4 + hi) ^ (lr & 7)) << 3)]);
            }
#pragma unroll
            for (int j = 0; j < 4; ++j) {
                const int r = wn + j * 16 + lr;
                bfr[j] = *(const bf16x8*)(&Bs[r * GBK + (((kk * 4 + hi) ^ (lr & 7)) << 3)]);
            }
#pragma unroll
            for (int i = 0; i < 4; ++i)
#pragma unroll
                for (int j = 0; j < 4; ++j)
                    acc[i][j] = __builtin_amdgcn_mfma_f32_16x16x32_bf16(af[i], bfr[j], acc[i][j], 0, 0, 0);
        }
        __syncthreads();
    }

    // epilogue: C/D layout col = lane&15, row = (lane>>4)*4 + reg  [m89-verified]
    const int crow = hi * 4;
    const int ccol = lr;
#pragma unroll
    for (int i = 0; i < 4; ++i) {
#pragma unroll
        for (int j = 0; j < 4; ++j) {
            const int gn = bn0 + wn + j * 16 + ccol;
            if (gn >= N) continue;
            const float bv = bias ? bias[gn] : 0.0f;
#pragma unroll
            for (int rr = 0; rr < 4; ++rr) {
                const int gm = bm0 + wm + i * 16 + crow + rr;
                if (gm >= M) continue;
                float v = acc[i][j][rr] + bv;
                if (ACT == 1) v = fmaxf(v, 0.0f);
                if (ACT == 2) v = gelu_exact(v);
                const long long idx = (long long)bz * sC + (long long)gm * N + gn;
                if (OUT_BF16) {
                    ((ushort*)Cv)[idx] = f2b(v);
                } else {
                    float* Cf = (float*)Cv;
                    if (ACCUM) Cf[idx] += v; else Cf[idx] = v;
                }
            }
        }
    }
}

// ============ transpose (+convert bf16) with zero-padded output rows ============
// in: (z, R, C) T;  out: (z, C, Rpad) bf16;  out[z][c][r] = in[z][r][c], 0 for r in [R,Rpad)
template<typename T>
__global__ __launch_bounds__(256) void transpose_pad_k(
    const T* __restrict__ in, ushort* __restrict__ out, int R, int C, int Rpad)
{
    __shared__ float tile[32][33];
    const long long ibase = (long long)blockIdx.z * R * C;
    const long long obase = (long long)blockIdx.z * C * Rpad;
    const int r0 = blockIdx.y * 32, c0 = blockIdx.x * 32;
    const int tx = threadIdx.x & 31, ty = threadIdx.x >> 5;
    for (int i = ty; i < 32; i += 8) {
        const int r = r0 + i, c = c0 + tx;
        float v = 0.0f;
        if (r < R && c < C) v = ld_as_f(in + ibase + (long long)r * C + c);
        tile[i][tx] = v;
    }
    __syncthreads();
    for (int i = ty; i < 32; i += 8) {
        const int c = c0 + i, r = r0 + tx;
        if (c < C && r < Rpad) out[obase + (long long)c * Rpad + r] = f2b(tile[tx][i]);
    }
}

// ============ fused: An[j][i] = (adj[j][i]+delta)*dinv[j]*dinv[i] -> attT[i][jpad] bf16 ============
__global__ __launch_bounds__(256) void normT_k(
    const float* __restrict__ att, const float* __restrict__ dinv, ushort* __restrict__ out)
{
    __shared__ float tile[32][33];
    const int b = blockIdx.z;
    const float* A = att + (long long)b * Nn * Nn;
    ushort* O = out + (long long)b * Nn * NnP;
    const int j0 = blockIdx.y * 32, i0 = blockIdx.x * 32;
    const int tx = threadIdx.x & 31, ty = threadIdx.x >> 5;
    for (int ii = ty; ii < 32; ii += 8) {
        const int j = j0 + ii, i = i0 + tx;
        float v = 0.0f;
        if (j < Nn && i < Nn) {
            v = A[(long long)j * Nn + i] + ((i == j) ? 1.0f : 0.0f);
            v *= dinv[b * Nn + j] * dinv[b * Nn + i];
        }
        tile[ii][tx] = v;
    }
    __syncthreads();
    for (int ii = ty; ii < 32; ii += 8) {
        const int i = i0 + ii, j = j0 + tx;
        if (i < Nn && j < NnP) O[(long long)i * NnP + j] = f2b(tile[tx][ii]);
    }
}

// ---------------- gate * emb -> bf16 ----------------
__global__ void gate_k(const float* __restrict__ x, const float* __restrict__ gw,
                       const float* __restrict__ gb, const float* __restrict__ emb,
                       ushort* __restrict__ X)
{
    const long long total = (long long)Bn * Nn * En;
    const long long idx = (long long)blockIdx.x * 256 + threadIdx.x;
    if (idx >= total) return;
    const int e = (int)(idx % En);
    const long long bn = idx / En;
    const int n = (int)(bn % Nn);
    const float t = x[bn] * gw[e] + gb[e];
    const float s = 1.0f / (1.0f + expf(-t));
    X[idx] = f2b(s * emb[(long long)n * En + e]);
}

// ---------------- mirror: lower blocks <- transpose(upper) ----------------
__global__ __launch_bounds__(256) void mirror_k(float* __restrict__ att)
{
    const int bi = blockIdx.x, bj = blockIdx.y;
    if (bi <= bj) return;
    float* A = att + (long long)blockIdx.z * Nn * Nn;
    __shared__ float t64[64][65];
    const int ti = threadIdx.x & 63;
    const int tj = threadIdx.x >> 6;
    const int i0 = bi * 64, j0 = bj * 64;
    for (int r = tj; r < 64; r += 4) {
        const int sr = j0 + r, sc = i0 + ti;
        t64[r][ti] = (sr < Nn && sc < Nn) ? A[(long long)sr * Nn + sc] : 0.0f;
    }
    __syncthreads();
    for (int r = tj; r < 64; r += 4) {
        const int dr = i0 + r, dc = j0 + ti;
        if (dr < Nn && dc < Nn) A[(long long)dr * Nn + dc] = t64[ti][r];
    }
}

// ---------------- top-k + masked softmax: one wave per row, binary search on bits ----------------
__global__ __launch_bounds__(256) void topk_softmax_k(float* __restrict__ att)
{
    const int wv = threadIdx.x >> 6;
    const int lane = threadIdx.x & 63;
    const long long row = (long long)blockIdx.x * 4 + wv;
    float* r = att + row * Nn;

    // load 32 values/lane as 8 float4 (slots c = lane*4 + i*256; i==7 invalid for lane>=52)
    float v[32];
    const bool v7 = (lane < 52);
#pragma unroll
    for (int i = 0; i < 8; ++i) {
        const int c = lane * 4 + i * 256;
        float4 f = {0.f, 0.f, 0.f, 0.f};
        if (i < 7 || v7) f = *(const float4*)(r + c);
        v[i * 4 + 0] = f.x * 0.125f;   // att / P
        v[i * 4 + 1] = f.y * 0.125f;
        v[i * 4 + 2] = f.z * 0.125f;
        v[i * 4 + 3] = f.w * 0.125f;
    }

    // wave max (sentinels are 0, never exceed a valid max since all values >= 0)
    float m = 0.0f;
#pragma unroll
    for (int i = 0; i < 32; ++i) m = fmaxf(m, v[i]);
#pragma unroll
    for (int s = 1; s < 64; s <<= 1) m = fmaxf(m, __shfl_xor(m, s));

    // binary search: largest u with count(bits(v) >= u) >= TOPK  (values >= 0 -> uint order)
    unsigned lo = 0, hi = __float_as_uint(m);
    while (lo < hi) {
        const unsigned mid = lo + ((hi - lo + 1) >> 1);   // mid >= 1, so 0-sentinels never count
        int c = 0;
#pragma unroll
        for (int i = 0; i < 32; ++i) c += (__float_as_uint(v[i]) >= mid) ? 1 : 0;
#pragma unroll
        for (int s = 1; s < 64; s <<= 1) c += __shfl_xor(c, s);
        if (c >= TOPK) lo = mid; else hi = mid - 1;
    }
    const float thr = __uint_as_float(lo);

    // exp over selected (exclude invalid slots: thr could be 0), wave sum
    float sum = 0.0f;
#pragma unroll
    for (int i = 0; i < 32; ++i) {
        const bool valid = (i < 28) || v7;                 // slots i>=28 belong to chunk 7
        const bool sel = valid && (v[i] >= thr);
        v[i] = sel ? expf(v[i] - m) : 0.0f;
        sum += v[i];
    }
#pragma unroll
    for (int s = 1; s < 64; s <<= 1) sum += __shfl_xor(sum, s);
    const float invZ = 1.0f / sum;

#pragma unroll
    for (int i = 0; i < 8; ++i) {
        const int c = lane * 4 + i * 256;
        if (i < 7 || v7) {
            float4 o = {v[i*4+0]*invZ, v[i*4+1]*invZ, v[i*4+2]*invZ, v[i*4+3]*invZ};
            *(float4*)(r + c) = o;
        }
    }
}

// ---------------- column sums of (adj + I) -> rsqrt ----------------
__global__ void colsum_k(const float* __restrict__ att, float* __restrict__ dinv)
{
    const int b = blockIdx.y;
    const int i = blockIdx.x * 256 + threadIdx.x;
    if (i >= Nn) return;
    const float* A = att + (long long)b * Nn * Nn;
    float s = 1.0f;
    for (int j = 0; j < Nn; ++j) s += A[(long long)j * Nn + i];
    dinv[b * Nn + i] = rsqrtf(s);
}

// ---------------- mean over nodes (2-level, atomic) ----------------
__global__ void mean_k(const float* __restrict__ nout, float* __restrict__ g)
{
    const int b = blockIdx.x;
    const int r0 = blockIdx.y * 200;
    const int col = threadIdx.x & 127, sub = threadIdx.x >> 7;   // 2 row-halves
    float s = 0.0f;
    for (int i = sub * 100; i < sub * 100 + 100; ++i)
        s += nout[((long long)b * Nn + r0 + i) * Dn + col];
    __shared__ float red[256];
    red[threadIdx.x] = s;
    __syncthreads();
    if (sub == 0) atomicAdd(&g[b * Dn + col], (red[col] + red[128 + col]) * (1.0f / Nn));
}

// ---------------- VIB head ----------------
__global__ void vib_k(const float* __restrict__ g, const float* __restrict__ eps,
                      float* __restrict__ mu_out, float* __restrict__ std_out,
                      float* __restrict__ z)
{
    const int t = blockIdx.x * 256 + threadIdx.x;
    if (t >= Bn * IBn) return;
    const int b = t / IBn, d = t % IBn;
    const float mu = g[b * Dn + d];
    const float x = g[b * Dn + IBn + d] - (float)IBn;
    const float sp = (x > 0.0f) ? (x + log1pf(expf(-x))) : log1pf(expf(x));
    mu_out[t] = mu;
    std_out[t] = sp;
    z[t] = mu + eps[t] * sp;
}

// ---------------- decoder layer 1 ----------------
__global__ void dec1_k(const float* __restrict__ z, const float* __restrict__ w1,
                       const float* __restrict__ b1, const float* __restrict__ gamma,
                       const float* __restrict__ beta, float* __restrict__ h)
{
    const int idx = blockIdx.x * 256 + threadIdx.x;
    if (idx >= Bn * HDE) return;
    const int b = idx / HDE, j = idx % HDE;
    float s = b1[j];
    for (int d = 0; d < IBn; ++d) s = fmaf(z[b * IBn + d], w1[d * HDE + j], s);
    s = s * (gamma[j] / sqrtf(1.0f + 1e-5f)) + beta[j];
    h[idx] = fmaxf(s, 0.0f);
}

// ---------------- decoder layer 2: all batches per thread, w2 read once coalesced ----------------
__global__ __launch_bounds__(256) void dec2_k(const float* __restrict__ h, const float* __restrict__ w2,
                                              const float* __restrict__ b2, float* __restrict__ out)
{
    __shared__ float hs[Bn * HDE];
    for (int i = threadIdx.x; i < Bn * HDE; i += 256) hs[i] = h[i];
    __syncthreads();
    const int n = blockIdx.x * 256 + threadIdx.x;
    if (n >= Nn) return;
    float acc[Bn];
    const float bb = b2[n];
#pragma unroll
    for (int b = 0; b < Bn; ++b) acc[b] = bb;
    for (int k = 0; k < HDE; ++k) {
        const float wv = w2[(long long)k * Nn + n];
#pragma unroll
        for (int b = 0; b < Bn; ++b) acc[b] = fmaf(hs[b * HDE + k], wv, acc[b]);
    }
#pragma unroll
    for (int b = 0; b < Bn; ++b) out[(long long)b * Nn + n] = fmaxf(acc[b], 0.0f);
}

// ---------------- host ----------------
extern "C" void kernel_launch(void* const* d_in, const int* in_sizes, int n_in,
                              void* d_out, int out_size, void* d_ws, size_t ws_size,
                              hipStream_t stream)
{
    const float* x1     = (const float*)d_in[0];
    const float* x2     = (const float*)d_in[1];
    const float* emb1   = (const float*)d_in[2];
    const float* gate_w = (const float*)d_in[3];
    const float* gate_b = (const float*)d_in[4];
    const float* enc_w1 = (const float*)d_in[5];
    const float* enc_b1 = (const float*)d_in[6];
    const float* enc_w2 = (const float*)d_in[7];
    const float* enc_b2 = (const float*)d_in[8];
    const float* gl_w   = (const float*)d_in[9];
    const float* g_w1   = (const float*)d_in[10];
    const float* g_b1   = (const float*)d_in[11];
    const float* g_w2   = (const float*)d_in[12];
    const float* g_b2   = (const float*)d_in[13];
    const float* g_w3   = (const float*)d_in[14];
    const float* g_b3   = (const float*)d_in[15];
    const float* dec_w1[2] = {(const float*)d_in[16], (const float*)d_in[22]};
    const float* dec_b1[2] = {(const float*)d_in[17], (const float*)d_in[23]};
    const float* dec_g [2] = {(const float*)d_in[18], (const float*)d_in[24]};
    const float* dec_be[2] = {(const float*)d_in[19], (const float*)d_in[25]};
    const float* dec_w2[2] = {(const float*)d_in[20], (const float*)d_in[26]};
    const float* dec_b2[2] = {(const float*)d_in[21], (const float*)d_in[27]};
    const float* epsv  [2] = {(const float*)d_in[28], (const float*)d_in[29]};
    const float* xv    [2] = {x1, x2};

    char* W = (char*)d_ws;
    const int MBN = Bn * Nn;  // 16000

    // ---- workspace layout (bytes) ----
    // R0 [0, 128MB): att fp32; early aliases Xg/henc; late aliases ZW/ZWT/bufB/Hout
    float*  att  = (float*) (W + 0);                     // 128,000,000
    ushort* Xg   = (ushort*)(W + 0);                     // 16,384,000 (dead before att)
    ushort* henc = (ushort*)(W + 16384000);              // 32,768,000 (dead before att)
    ushort* ZW   = (ushort*)(W + 0);                     // 16,384,000 (att dead post-normT)
    ushort* ZWT  = (ushort*)(W + 16384000);              // 16,777,216 (8 x 512 x 2048)
    ushort* bufB = (ushort*)(W + 33161216);              // 16,384,000
    float*  Hout = (float*) (W + 49545216);              //  8,192,000
    // R1 [128MB, 193.5MB): F2 bf16 (8,2000,2048); later attT bf16 (8,2000,2048)
    ushort* F2   = (ushort*)(W + 128000000);             // 65,536,000
    ushort* attT = (ushort*)(W + 128000000);             // 65,536,000 (F2 dead)
    // R2 [193.5MB, ...): persistent small buffers
    ushort* Hb     = (ushort*)(W + 193536000);           // 4,096,000  (16000x128 bf16)
    ushort* enc_w1T= (ushort*)(W + 197632000);           // (1024,512)
    ushort* enc_w2T= (ushort*)(W + 198680576);           // (128,1024)
    ushort* glT    = (ushort*)(W + 198942720);           // (8,512,128)
    ushort* g_w1T  = (ushort*)(W + 199991296);           // (512,128)
    ushort* g_w2T  = (ushort*)(W + 200122368);           // (512,512)
    ushort* g_w3T  = (ushort*)(W + 200646656);           // (128,512)
    float*  dinv   = (float*) (W + 200777728);           // 16000
    float*  gmean  = (float*) (W + 200841728);           // 8x128
    float*  zbuf   = (float*) (W + 200845824);           // 8x64
    float*  hdec   = (float*) (W + 200847872);           // 8x1024

    const long long sAtt  = (long long)Nn * Nn;          // C stride (fp32 att)
    const long long sF2   = (long long)Nn * NnP;         // per-batch stride in F2/attT
    const long long sZWT  = (long long)HDn * NnP;
    const long long sBufB = (long long)Nn * HDn;
    const long long sZT3  = (long long)Dn * NnP;
    const long long sHout = (long long)Nn * Dn;

    // ---- weight prep (no padding needed: K multiples of 64 already) ----
    transpose_pad_k<float><<<dim3(CDIV(HEN,32), CDIV(En,32), 1), 256, 0, stream>>>(enc_w1, enc_w1T, En, HEN, En);
    transpose_pad_k<float><<<dim3(CDIV(Dn,32),  CDIV(HEN,32),1), 256, 0, stream>>>(enc_w2, enc_w2T, HEN, Dn, HEN);
    transpose_pad_k<float><<<dim3(CDIV(HDn,32), CDIV(Dn,32), Pn),256, 0, stream>>>(gl_w,   glT,     Dn,  HDn, Dn);
    transpose_pad_k<float><<<dim3(CDIV(HDn,32), CDIV(Dn,32), 1), 256, 0, stream>>>(g_w1,   g_w1T,   Dn,  HDn, Dn);
    transpose_pad_k<float><<<dim3(CDIV(HDn,32), CDIV(HDn,32),1), 256, 0, stream>>>(g_w2,   g_w2T,   HDn, HDn, HDn);
    transpose_pad_k<float><<<dim3(CDIV(Dn,32),  CDIV(HDn,32),1), 256, 0, stream>>>(g_w3,   g_w3T,   HDn, Dn, HDn);

    for (int g = 0; g < 2; ++g) {
        float* xrec_out = (float*)d_out + g * MBN;
        float* mu_out   = (float*)d_out + 2 * MBN + g * 2 * Bn * IBn;
        float* std_out  = mu_out + Bn * IBn;

        // ---- encoder ----
        gate_k<<<CDIV((long long)MBN * En, 256), 256, 0, stream>>>(xv[g], gate_w, gate_b, emb1, Xg);
        mgemm_k<2,false,false,true><<<dim3(CDIV(MBN,GBM), CDIV(HEN,GBN), 1), 256, 0, stream>>>(
            Xg, enc_w1T, enc_b1, henc, MBN, HEN, En, 0, 0, 0);
        mgemm_k<0,false,false,true><<<dim3(CDIV(MBN,GBM), CDIV(Dn,GBN), 1), 256, 0, stream>>>(
            henc, enc_w2T, enc_b2, Hb, MBN, Dn, HEN, 0, 0, 0);

        // ---- adjacency: att = sum_p relu(H gl_w[p]) relu(H gl_w[p])^T (2 concat-K groups) ----
        for (int g2 = 0; g2 < 2; ++g2) {
            mgemm_k<1,false,false,true><<<dim3(CDIV(MBN,GBM), CDIV(NnP,GBN), 1), 256, 0, stream>>>(
                Hb, glT + (long long)g2 * NnP * Dn, nullptr, F2, MBN, NnP, Dn, 0, 0, 0);
            if (g2 == 0)
                mgemm_k<0,false,true,false><<<dim3(CDIV(Nn,GBM), CDIV(Nn,GBN), Bn), 256, 0, stream>>>(
                    F2, F2, nullptr, att, Nn, Nn, NnP, sF2, sF2, sAtt);
            else
                mgemm_k<0,true,true,false><<<dim3(CDIV(Nn,GBM), CDIV(Nn,GBN), Bn), 256, 0, stream>>>(
                    F2, F2, nullptr, att, Nn, Nn, NnP, sF2, sF2, sAtt);
        }
        mirror_k<<<dim3(CDIV(Nn,64), CDIV(Nn,64), Bn), 256, 0, stream>>>(att);
        topk_softmax_k<<<CDIV(MBN,4), 256, 0, stream>>>(att);

        // ---- GCN normalization (colsum on softmax att; norm+transpose+pad fused) ----
        colsum_k<<<dim3(CDIV(Nn,256), Bn, 1), 256, 0, stream>>>(att, dinv);
        normT_k<<<dim3(CDIV(Nn,32), CDIV(NnP,32), Bn), 256, 0, stream>>>(att, dinv, attT);

        // ---- GCN layer 1 ----
        mgemm_k<0,false,false,true><<<dim3(CDIV(MBN,GBM), CDIV(HDn,GBN), 1), 256, 0, stream>>>(
            Hb, g_w1T, nullptr, ZW, MBN, HDn, Dn, 0, 0, 0);
        transpose_pad_k<ushort><<<dim3(CDIV(HDn,32), CDIV(NnP,32), Bn), 256, 0, stream>>>(ZW, ZWT, Nn, HDn, NnP);
        mgemm_k<1,false,false,true><<<dim3(CDIV(Nn,GBM), CDIV(HDn,GBN), Bn), 256, 0, stream>>>(
            attT, ZWT, g_b1, bufB, Nn, HDn, NnP, sF2, sZWT, sBufB);
        // ---- GCN layer 2 ----
        mgemm_k<0,false,false,true><<<dim3(CDIV(MBN,GBM), CDIV(HDn,GBN), 1), 256, 0, stream>>>(
            bufB, g_w2T, nullptr, ZW, MBN, HDn, HDn, 0, 0, 0);
        transpose_pad_k<ushort><<<dim3(CDIV(HDn,32), CDIV(NnP,32), Bn), 256, 0, stream>>>(ZW, ZWT, Nn, HDn, NnP);
        mgemm_k<1,false,false,true><<<dim3(CDIV(Nn,GBM), CDIV(HDn,GBN), Bn), 256, 0, stream>>>(
            attT, ZWT, g_b2, bufB, Nn, HDn, NnP, sF2, sZWT, sBufB);
        // ---- GCN layer 3 ----
        mgemm_k<0,false,false,true><<<dim3(CDIV(MBN,GBM), CDIV(Dn,GBN), 1), 256, 0, stream>>>(
            bufB, g_w3T, nullptr, ZW, MBN, Dn, HDn, 0, 0, 0);
        transpose_pad_k<ushort><<<dim3(CDIV(Dn,32), CDIV(NnP,32), Bn), 256, 0, stream>>>(ZW, ZWT, Nn, Dn, NnP);
        mgemm_k<0,false,false,false><<<dim3(CDIV(Nn,GBM), CDIV(Dn,GBN), Bn), 256, 0, stream>>>(
            attT, ZWT, g_b3, Hout, Nn, Dn, NnP, sF2, sZT3, sHout);

        // ---- readout + VIB + decoder ----
        hipMemsetAsync(gmean, 0, Bn * Dn * sizeof(float), stream);
        mean_k<<<dim3(Bn, 10, 1), 256, 0, stream>>>(Hout, gmean);
        vib_k<<<CDIV(Bn * IBn, 256), 256, 0, stream>>>(gmean, epsv[g], mu_out, std_out, zbuf);
        dec1_k<<<CDIV(Bn * HDE, 256), 256, 0, stream>>>(zbuf, dec_w1[g], dec_b1[g], dec_g[g], dec_be[g], hdec);
        dec2_k<<<CDIV(Nn, 256), 256, 0, stream>>>(hdec, dec_w2[g], dec_b2[g], xrec_out);
    }
}